// Round 2
// baseline (498.987 us; speedup 1.0000x reference)
//
#include <hip/hip_runtime.h>

// HybridAttention (fp32 I/O, bf16 MFMA internals):
// x -> cast bf16 -> QKV proj (MFMA GEMM, fused N=3072, split-store Q/K/V bf16)
// -> fused {G=Q K^T tile + diagonal-sum} (G never materialized) -> bandpass
// filter (g = irfft of band mask) -> top-6 + softmax -> context = weighted V
// row-gather (bf16) -> out GEMM (+bias+residual, fp32 into d_out) -> LayerNorm
// in-place on d_out. fp32 accumulate everywhere. ws need = 142,741,952 B.
//
// R8: overlap LDS drain with MFMA. R7's 4-phase loop had 8 barriers/K-tile and
// lgkmcnt(0) before every MFMA cluster -> LDS fragment delivery (~2300 cyc/CU/
// tile) fully serialized against MFMA (~2480 cyc) -> 6050 cyc/tile measured,
// MfmaUtil 36%. R8: (1) rotate next tile's first fragment reads to before the
// current tile's LAST MFMA cluster (operands already in regs) so the drain
// hides under MFMA; (2) kk-split phases, each <=8 ds_reads, read order
// av0,bv0..3,av1..3 so first MFMA group needs only 5 arrivals (compiler emits
// counted lgkmcnt per dep); (3) barriers cut 8 -> 3 per tile (end-P2 = B free,
// end-P3 = A free w/ explicit lgkmcnt(0), post-vmcnt(6) = next tile staged).
// Stage slots: A1(t+1)@P2, B0(t+2)@P3, B1+A0(t+2)@P4; vmcnt(6) = 3 half-tiles
// in flight, never drained in steady state. XOR-swizzled LDS as in R6/R7.

typedef unsigned short u16;
typedef unsigned int   u32;
typedef __attribute__((ext_vector_type(8))) __bf16 bf16x8;
typedef __attribute__((ext_vector_type(4))) float  floatx4;

#define HIDn 1024

__device__ __forceinline__ u16 f2b(float f){ u32 i = __float_as_uint(f); return (u16)((i + 0x7fffu + ((i>>16)&1u)) >> 16); }

__device__ __forceinline__ void gl_lds16(const u16* g, u16* l){
  __builtin_amdgcn_global_load_lds((__attribute__((address_space(1))) const void*)g,
                                   (__attribute__((address_space(3))) void*)l, 16, 0, 0);
}

__device__ __forceinline__ void bar(){
  asm volatile("" ::: "memory");
  __builtin_amdgcn_s_barrier();
  asm volatile("" ::: "memory");
}

// ---------------------------------------------------------------- ws guard
__global__ void fill_kernel(float* __restrict__ out, float v, int n)
{
  const int i = blockIdx.x*blockDim.x + threadIdx.x;
  if (i < n) out[i] = v;
}

// ---------------------------------------------------------------- cast x -> bf16
__global__ __launch_bounds__(256)
void cast_kernel(const float* __restrict__ x, u16* __restrict__ xb)
{
  const int i = blockIdx.x*256 + threadIdx.x;   // 2,097,152 threads x 8 floats
  const float4* xp = (const float4*)x;
  const float4 a = xp[2*i], b = xp[2*i+1];
  uint4 o;
  o.x = (u32)f2b(a.x) | ((u32)f2b(a.y)<<16);
  o.y = (u32)f2b(a.z) | ((u32)f2b(a.w)<<16);
  o.z = (u32)f2b(b.x) | ((u32)f2b(b.y)<<16);
  o.w = (u32)f2b(b.z) | ((u32)f2b(b.w)<<16);
  ((uint4*)xb)[i] = o;
}

// ---------------------------------------------------------------- transpose+cast
// WqkvT (3072 x 1024, n-major, bf16) and WdT (1024 x 1024, bf16) from fp32 W.
__global__ __launch_bounds__(1024)
void transpose_kernel(const float* __restrict__ Wq, const float* __restrict__ Wk,
                      const float* __restrict__ Wv, const float* __restrict__ Wd,
                      u16* __restrict__ WqkvT, u16* __restrict__ WdT)
{
  __shared__ float tile[32][33];
  const int mat = blockIdx.z;
  const float* W = (mat==0)?Wq:(mat==1)?Wk:(mat==2)?Wv:Wd;
  const int k = blockIdx.y*32 + threadIdx.y;
  const int n = blockIdx.x*32 + threadIdx.x;
  tile[threadIdx.y][threadIdx.x] = W[(long)k*HIDn + n];
  __syncthreads();
  const int on = blockIdx.x*32 + threadIdx.y;
  const int ok = blockIdx.y*32 + threadIdx.x;
  const u16 val = f2b(tile[threadIdx.x][threadIdx.y]);
  if (mat < 3) WqkvT[(long)(mat*HIDn + on)*HIDn + ok] = val;
  else         WdT[(long)on*HIDn + ok] = val;
}

// ---------------------------------------------------------------- gf + zero c
// g[d] = (2*sum_{f=205..511} cos(2 pi f d/1024) + (-1)^d) / 1024^2
__global__ __launch_bounds__(1024)
void gf_kernel(float* __restrict__ gf, float* __restrict__ c)
{
  const int d = threadIdx.x;
  float s = 0.f;
  for (int f = 205; f < 512; ++f){
    int p = (f*d) & 1023;
    s += cosf(6.283185307179586f * (float)p * (1.0f/1024.0f));
  }
  gf[d] = (2.f*s + ((d & 1) ? -1.f : 1.f)) * (1.0f/1048576.0f);
  #pragma unroll
  for (int b = 0; b < 16; ++b) c[b*1024 + d] = 0.f;
}

// ---------------------------------------------------------------- MFMA GEMM
// C(M x N) = A(M x K) * Bt(N x K)^T ; bf16 in, fp32 acc. 256x256 tile, 8 waves
// (2Mx4N), per-wave 128x64 (acc[8][4] 16x16x32 frags), BK=64, rotated 4-phase
// schedule (see header). Requires K % 64 == 0, K >= 128.
// EPI 0: +fp32 bias (select by bx>>2), bf16 split-store to C0/o1/o2 (Q/K/V).
// EPI 2: +fp32 bias +fp32 resid, fp32 out (hidden+residual -> d_out).
// EPI 3: no C store; diagonal-sum tile into cbuf[bz*1024 + d] (atomics).
template<int EPI>
__global__ __launch_bounds__(512, 2)
void gemm_mfma(const u16* __restrict__ A, int lda, long sA,
               const u16* __restrict__ Bt, int ldb, long sB,
               void* __restrict__ C0, u16* __restrict__ o1, u16* __restrict__ o2,
               int ldc, int K,
               const float* __restrict__ b0, const float* __restrict__ b1,
               const float* __restrict__ b2, const float* __restrict__ resid,
               float* __restrict__ cbuf)
{
  __shared__ __align__(16) u16 As[2][16384];   // 2 x (256 rows x 64 k)
  __shared__ __align__(16) u16 Bs[2][16384];
  __shared__ float bins[512];

  const int bx = blockIdx.x, by = blockIdx.y, bz = blockIdx.z;
  const int tid  = threadIdx.x;
  const int wave = tid >> 6, lane = tid & 63;
  const int waveM = wave >> 2, waveN = wave & 3;
  const int qd = lane >> 4, ln = lane & 15, rl = ln & 7;
  const u16* Ab = A  + (long)bz * sA;
  const u16* Bb = Bt + (long)bz * sB;
  const int aRow0 = by * 256, bRow0 = bx * 256;
  const int nt = K >> 6;

  // staging: slot s = wave*128 + lane within a 128-row half (8 chunks/row)
  const int s0 = wave*128 + lane;
  const int r0 = s0 >> 3, r1 = r0 + 8;
  const int kc = ((s0 & 7) ^ (r0 & 7)) * 8;          // pre-swizzled source chunk
  const long aOff0 = (long)(aRow0 + r0)*lda + kc;
  const long aOff1 = (long)(aRow0 + r1)*lda + kc;
  const long bOff0 = (long)(bRow0 + r0)*ldb + kc;
  const long bOff1 = (long)(bRow0 + r1)*ldb + kc;
  const int dstW = wave*1024;                         // u16, wave-uniform

#define STAGE_A(p, h, kt) do{ \
    gl_lds16(Ab + aOff0 + (long)(h)*128*lda + (kt), &As[p][(h)*8192 + dstW]); \
    gl_lds16(Ab + aOff1 + (long)(h)*128*lda + (kt), &As[p][(h)*8192 + dstW + 512]); }while(0)
#define STAGE_B(p, h, kt) do{ \
    gl_lds16(Bb + bOff0 + (long)(h)*128*ldb + (kt), &Bs[p][(h)*8192 + dstW]); \
    gl_lds16(Bb + bOff1 + (long)(h)*128*ldb + (kt), &Bs[p][(h)*8192 + dstW + 512]); }while(0)

  if (EPI == 3) bins[tid] = 0.f;       // synced by prologue barrier

  floatx4 acc[8][4];
  const floatx4 z4 = {0.f, 0.f, 0.f, 0.f};
  #pragma unroll
  for (int i=0;i<8;++i)
    #pragma unroll
    for (int j=0;j<4;++j) acc[i][j] = z4;

  // read addressing: row R frag at u16 offset R*64 + ((chunk)^(R&7))*8
  const int aRd = (waveM*128 + ln)*64;   // + mi*1024 (+4096 for m-half 1)
  const int bRd = (waveN*64  + ln)*64;   // + ni*1024
  const int csw0 = ((0 + qd) ^ rl) * 8;  // kk=0 chunk
  const int csw1 = ((4 + qd) ^ rl) * 8;  // kk=1 chunk

  // ---- prologue: tile0 {B0,B1,A0,A1}, tile1 {B0,B1,A0}; wait tile0 (vmcnt 6)
  STAGE_B(0,0,0); STAGE_B(0,1,0); STAGE_A(0,0,0); STAGE_A(0,1,0);
  STAGE_B(1,0,64); STAGE_B(1,1,64); STAGE_A(1,0,64);
  asm volatile("s_waitcnt vmcnt(6)" ::: "memory");
  __builtin_amdgcn_s_barrier();
  asm volatile("" ::: "memory");

  bf16x8 avA[4], avB[4], bvA[4], bvB[4];
  // P1-reads for t=0 (kk0, m-half0 A rows + all B n-frags)
  {
    const u16* Ap = &As[0][0]; const u16* Bp = &Bs[0][0];
    avA[0] = *(const bf16x8*)(Ap + aRd + 0*1024 + csw0);
    #pragma unroll
    for (int ni=0;ni<4;++ni) bvA[ni] = *(const bf16x8*)(Bp + bRd + ni*1024 + csw0);
    #pragma unroll
    for (int mi=1;mi<4;++mi) avA[mi] = *(const bf16x8*)(Ap + aRd + mi*1024 + csw0);
  }
  __builtin_amdgcn_sched_barrier(0);

  for (int t = 0; t < nt; ++t){
    const int p = t & 1;
    const u16* Ap = &As[p][0];
    const u16* Bp = &Bs[p][0];
    const int k1 = (t+1) << 6, k2 = (t+2) << 6;

    // ---- P1: MFMA kk0 x m-half0 (operands loaded at end of prev iteration)
    __builtin_amdgcn_s_setprio(1);
    #pragma unroll
    for (int mi=0;mi<4;++mi){
      #pragma unroll
      for (int ni=0;ni<4;++ni)
        acc[mi][ni] = __builtin_amdgcn_mfma_f32_16x16x32_bf16(avA[mi], bvA[ni], acc[mi][ni], 0,0,0);
      __builtin_amdgcn_sched_barrier(0);
    }
    __builtin_amdgcn_s_setprio(0);

    // ---- P2: read kk1 m-half0 + kk1 B; stage A1(t+1); MFMA kk1 x m-half0
    avB[0] = *(const bf16x8*)(Ap + aRd + 0*1024 + csw1);
    #pragma unroll
    for (int ni=0;ni<4;++ni) bvB[ni] = *(const bf16x8*)(Bp + bRd + ni*1024 + csw1);
    #pragma unroll
    for (int mi=1;mi<4;++mi) avB[mi] = *(const bf16x8*)(Ap + aRd + mi*1024 + csw1);
    if (t+1 < nt) STAGE_A(p^1, 1, k1);
    __builtin_amdgcn_sched_barrier(0);
    __builtin_amdgcn_s_setprio(1);
    #pragma unroll
    for (int mi=0;mi<4;++mi){
      #pragma unroll
      for (int ni=0;ni<4;++ni)
        acc[mi][ni] = __builtin_amdgcn_mfma_f32_16x16x32_bf16(avB[mi], bvB[ni], acc[mi][ni], 0,0,0);
      __builtin_amdgcn_sched_barrier(0);
    }
    __builtin_amdgcn_s_setprio(0);
    bar();                               // B reads of tile t done -> B halves free

    // ---- P3: read m-half1 (both kk); stage B0(t+2); MFMA kk0 x m-half1
    #pragma unroll
    for (int mi=0;mi<4;++mi) avA[mi] = *(const bf16x8*)(Ap + aRd + 4096 + mi*1024 + csw0);
    #pragma unroll
    for (int mi=0;mi<4;++mi) avB[mi] = *(const bf16x8*)(Ap + aRd + 4096 + mi*1024 + csw1);
    if (t+2 < nt) STAGE_B(p, 0, k2);
    __builtin_amdgcn_sched_barrier(0);
    __builtin_amdgcn_s_setprio(1);
    #pragma unroll
    for (int mi=0;mi<4;++mi){
      #pragma unroll
      for (int ni=0;ni<4;++ni)
        acc[4+mi][ni] = __builtin_amdgcn_mfma_f32_16x16x32_bf16(avA[mi], bvA[ni], acc[4+mi][ni], 0,0,0);
      __builtin_amdgcn_sched_barrier(0);
    }
    __builtin_amdgcn_s_setprio(0);
    asm volatile("s_waitcnt lgkmcnt(0)" ::: "memory");   // avB delivered too
    __builtin_amdgcn_sched_barrier(0);
    bar();                               // A reads of tile t done -> A halves free

    // ---- P4: stage B1+A0(t+2); counted vmcnt; boundary bar; issue next tile's
    //          P1-reads; then MFMA kk1 x m-half1 (operands already in regs).
    if (t+2 < nt){
      STAGE_B(p, 1, k2); STAGE_A(p, 0, k2);
      asm volatile("s_waitcnt vmcnt(6)" ::: "memory");   // tile t+1 fully staged
    } else if (t+1 < nt){
      asm volatile("s_waitcnt vmcnt(0)" ::: "memory");   // drain tail
    }
    if (t+1 < nt){
      bar();                             // next tile's buffer ready
      const u16* An = &As[p^1][0];
      const u16* Bn = &Bs[p^1][0];
      avA[0] = *(const bf16x8*)(An + aRd + 0*1024 + csw0);
      #pragma unroll
      for (int ni=0;ni<4;++ni) bvA[ni] = *(const bf16x8*)(Bn + bRd + ni*1024 + csw0);
      #pragma unroll
      for (int mi=1;mi<4;++mi) avA[mi] = *(const bf16x8*)(An + aRd + mi*1024 + csw0);
      __builtin_amdgcn_sched_barrier(0);
    }
    __builtin_amdgcn_s_setprio(1);
    #pragma unroll
    for (int mi=0;mi<4;++mi){
      #pragma unroll
      for (int ni=0;ni<4;++ni)
        acc[4+mi][ni] = __builtin_amdgcn_mfma_f32_16x16x32_bf16(avB[mi], bvB[ni], acc[4+mi][ni], 0,0,0);
      __builtin_amdgcn_sched_barrier(0);
    }
    __builtin_amdgcn_s_setprio(0);
  }
#undef STAGE_A
#undef STAGE_B

  if (EPI == 3){
    // G[l][m] at frag(mi,ni) reg r lane(qd,ln):
    //   l-m = (aRow0-bRow0) + 128*waveM - 64*waveN + 16*(mi-ni) + 4*qd + r - ln
    float dsum[11][4];
    #pragma unroll
    for (int dd=0; dd<11; ++dd)
      #pragma unroll
      for (int r=0;r<4;++r) dsum[dd][r] = 0.f;
    #pragma unroll
    for (int mi=0;mi<8;++mi)
      #pragma unroll
      for (int ni=0;ni<4;++ni){
        const int dd = mi - ni + 3;
        #pragma unroll
        for (int r=0;r<4;++r) dsum[dd][r] += acc[mi][ni][r];
      }
    const int base = 255 + 128*waveM - 64*waveN + 4*qd - ln;
    #pragma unroll
    for (int dd=0; dd<11; ++dd)
      #pragma unroll
      for (int r=0;r<4;++r)
        atomicAdd(&bins[base + 16*(dd-3) + r], dsum[dd][r]);
    __syncthreads();
    if (tid < 511){
      const int d = (aRow0 - bRow0 + tid - 255) & 1023;
      atomicAdd(cbuf + bz*1024 + d, bins[tid]);
    }
    return;
  }

  // epilogue: C/D layout col = lane&15, row = (lane>>4)*4 + reg
  if (EPI == 0){
    const int which = bx >> 2;                 // 256-tile never crosses 1024
    const float* bp = (which==0) ? b0 : ((which==1) ? b1 : b2);
    u16* Cb = (which==0) ? (u16*)C0 : ((which==1) ? o1 : o2);
    const int nb = bRow0 & 1023;
    #pragma unroll
    for (int mi=0;mi<8;++mi){
      const int gm = aRow0 + waveM*128 + mi*16 + qd*4;
      #pragma unroll
      for (int ni=0;ni<4;++ni){
        const int nl = nb + waveN*64 + ni*16 + ln;
        const float bias = bp[nl];
        #pragma unroll
        for (int r=0;r<4;++r) Cb[(long)(gm+r)*ldc + nl] = f2b(acc[mi][ni][r] + bias);
      }
    }
  } else {  // EPI == 2
    float* C = (float*)C0;
    #pragma unroll
    for (int mi=0;mi<8;++mi){
      const int gm = aRow0 + waveM*128 + mi*16 + qd*4;
      #pragma unroll
      for (int ni=0;ni<4;++ni){
        const int gn = bRow0 + waveN*64 + ni*16 + ln;
        const float bias = b0[gn];
        #pragma unroll
        for (int r=0;r<4;++r)
          C[(long)(gm+r)*ldc + gn] = acc[mi][ni][r] + bias + resid[(long)(gm+r)*ldc + gn];
      }
    }
  }
}

// ---------------------------------------------------------------- filter
// mv[b,n] = sum_m c[b,m] * gf[(n-m)&1023]
__global__ __launch_bounds__(1024)
void filter_kernel(const float* __restrict__ c, const float* __restrict__ gf,
                   float* __restrict__ mv)
{
  __shared__ float carr[1024];
  __shared__ float gsh[1024];
  const int b = blockIdx.x, l = threadIdx.x;
  carr[l] = c[b*1024 + l]; gsh[l] = gf[l];
  __syncthreads();
  float o = 0.f;
  #pragma unroll 4
  for (int m = 0; m < 1024; ++m) o += carr[m] * gsh[(l - m) & 1023];
  mv[b*1024 + l] = o;
}

// ---------------------------------------------------------------- top-6 + softmax
__global__ __launch_bounds__(1024)
void topk_kernel(const float* __restrict__ mv, int* __restrict__ idxout,
                 float* __restrict__ wout)
{
  __shared__ float vals[1024];
  __shared__ float rv[1024];
  __shared__ int   ri[1024];
  __shared__ int   chosen[6];
  const int t = threadIdx.x;
  float s = 0.f;
  #pragma unroll
  for (int b = 0; b < 16; ++b) s += mv[b*1024 + t];
  vals[t] = s;
  __syncthreads();
  for (int r = 0; r < 6; ++r){
    rv[t] = vals[t]; ri[t] = t; __syncthreads();
    for (int off = 512; off > 0; off >>= 1){
      if (t < off){
        const float v2 = rv[t+off]; const int i2 = ri[t+off];
        if (v2 > rv[t] || (v2 == rv[t] && i2 < ri[t])){ rv[t] = v2; ri[t] = i2; }
      }
      __syncthreads();
    }
    if (t == 0){ chosen[r] = ri[0]; idxout[r] = ri[0]; }
    __syncthreads();
    if (t == chosen[r]) vals[t] = -3.0e38f;
    __syncthreads();
  }
  if (t < 16){
    float w[6]; float mx = -3.0e38f;
    #pragma unroll
    for (int i = 0; i < 6; ++i){ w[i] = mv[t*1024 + chosen[i]]; mx = fmaxf(mx, w[i]); }
    float sum = 0.f;
    #pragma unroll
    for (int i = 0; i < 6; ++i){ w[i] = expf(w[i] - mx); sum += w[i]; }
    #pragma unroll
    for (int i = 0; i < 6; ++i) wout[t*6 + i] = w[i] / sum;
  }
}

// ---------------------------------------------------------------- context gather
// CT[b*1024+l, :] = sum_i w[b,i] * V[b, (l+idx_i)&1023, :]   (bf16 in/out)
__global__ __launch_bounds__(256)
void context_kernel(const u16* __restrict__ Vb, const int* __restrict__ idx,
                    const float* __restrict__ w, u16* __restrict__ CT)
{
  const int row = blockIdx.x*2 + (threadIdx.x >> 7);
  const int b = row >> 10, l = row & 1023;
  const int t = threadIdx.x & 127;       // chunk of 8 channels
  float wl[6]; int id[6];
  #pragma unroll
  for (int i = 0; i < 6; ++i){ id[i] = idx[i]; wl[i] = w[b*6 + i]; }
  float acc[8] = {0,0,0,0,0,0,0,0};
  #pragma unroll
  for (int i = 0; i < 6; ++i){
    const long src = (long)b*1024 + ((l + id[i]) & 1023);
    const uint4 pk = *(const uint4*)(Vb + src*1024 + t*8);
    const float ww = wl[i];
    union{float f; u32 u;} cv;
    cv.u = pk.x<<16;          acc[0] += ww*cv.f;
    cv.u = pk.x & 0xffff0000u; acc[1] += ww*cv.f;
    cv.u = pk.y<<16;          acc[2] += ww*cv.f;
    cv.u = pk.y & 0xffff0000u; acc[3] += ww*cv.f;
    cv.u = pk.z<<16;          acc[4] += ww*cv.f;
    cv.u = pk.z & 0xffff0000u; acc[5] += ww*cv.f;
    cv.u = pk.w<<16;          acc[6] += ww*cv.f;
    cv.u = pk.w & 0xffff0000u; acc[7] += ww*cv.f;
  }
  uint4 o;
  o.x = (u32)f2b(acc[0]) | ((u32)f2b(acc[1])<<16);
  o.y = (u32)f2b(acc[2]) | ((u32)f2b(acc[3])<<16);
  o.z = (u32)f2b(acc[4]) | ((u32)f2b(acc[5])<<16);
  o.w = (u32)f2b(acc[6]) | ((u32)f2b(acc[7])<<16);
  *(uint4*)(CT + (long)row*1024 + t*8) = o;
}

// ---------------------------------------------------------------- layernorm (in-place fp32)
__global__ __launch_bounds__(256)
void ln_kernel(float* __restrict__ io, const float* __restrict__ gamma,
               const float* __restrict__ beta)
{
  __shared__ float s1[256];
  __shared__ float s2[256];
  const int row = blockIdx.x, t = threadIdx.x;
  float4 v = ((const float4*)(io + (long)row*1024))[t];
  s1[t] = v.x+v.y+v.z+v.w;
  s2[t] = v.x*v.x+v.y*v.y+v.z*v.z+v.w*v.w;
  __syncthreads();
  for (int off = 128; off > 0; off >>= 1){
    if (t < off){ s1[t] += s1[t+off]; s2[t] += s2[t+off]; }
    __syncthreads();
  }
  const float mu  = s1[0] * (1.f/1024.f);
  const float var = fmaxf(s2[0] * (1.f/1024.f) - mu*mu, 0.f);
  const float rstd = rsqrtf(var + 1e-12f);
  const float4 g  = ((const float4*)gamma)[t];
  const float4 be = ((const float4*)beta)[t];
  float4 o;
  o.x = (v.x-mu)*rstd*g.x + be.x;
  o.y = (v.y-mu)*rstd*g.y + be.y;
  o.z = (v.z-mu)*rstd*g.z + be.z;
  o.w = (v.w-mu)*rstd*g.w + be.w;
  ((float4*)(io + (long)row*1024))[t] = o;
}

// ---------------------------------------------------------------- launch
extern "C" void kernel_launch(void* const* d_in, const int* in_sizes, int n_in,
                              void* d_out, int out_size, void* d_ws, size_t ws_size,
                              hipStream_t stream)
{
  (void)in_sizes; (void)n_in;
  const float* x     = (const float*)d_in[0];
  // d_in[1] attention_mask: zeros, unused by the reference math
  const float* Wq    = (const float*)d_in[2];
  const float* bq    = (const float*)d_in[3];
  const float* Wk    = (const float*)d_in[4];
  const float* bk    = (const float*)d_in[5];
  const float* Wv    = (const float*)d_in[6];
  const float* bv    = (const float*)d_in[7];
  const float* Wd    = (const float*)d_in[8];
  const float* bd    = (const float*)d_in[9];
  const float* gamma = (const float*)d_in[10];
  const float* beta  = (const float*)d_in[11];
  float* outp = (float*)d_out;

  // ws layout (bytes), total 142,741,952:
  // xb 32M | Qb 32M | Kb 32M | Vb 32M | WqkvT 6M | WdT 2M | cbuf 64K | mv 64K | gf 4K | idx | w
  const size_t NEED = 142741952UL;
  if (ws_size < NEED){
    // guard: encode ws_size into the output so a failing absmax reveals it
    const int n = out_size/2;
    fill_kernel<<<(n+255)/256, 256, 0, stream>>>(outp, (float)ws_size, n);
    return;
  }
  char* ws = (char*)d_ws;
  u16*  xb    = (u16*)(ws);
  u16*  Qb    = (u16*)(ws + 33554432L);
  u16*  Kb    = (u16*)(ws + 67108864L);
  u16*  Vb    = (u16*)(ws + 100663296L);
  u16*  WqkvT = (u16*)(ws + 134217728L);
  u16*  WdT   = (u16*)(ws + 140509184L);
  float* cbuf = (float*)(ws + 142606336L);
  float* mv   = (float*)(ws + 142671872L);
  float* gf   = (float*)(ws + 142737408L);
  int*   idxb = (int*)  (ws + 142741504L);
  float* wsm  = (float*)(ws + 142741568L);
  u16*  CT    = Qb;   // reuse: Q's last reader is the G-gemm

  cast_kernel<<<8192, 256, 0, stream>>>(x, xb);
  transpose_kernel<<<dim3(32,32,4), dim3(32,32), 0, stream>>>(Wq, Wk, Wv, Wd, WqkvT, WdT);
  gf_kernel<<<1, 1024, 0, stream>>>(gf, cbuf);

  // Q|K|V = x @ [Wq|Wk|Wv] + bias (M=16384, N=3072, K=1024), bf16 split-store
  gemm_mfma<0><<<dim3(12,64,1), 512, 0, stream>>>(
      xb, 1024, 0L, WqkvT, 1024, 0L, Qb, Kb, Vb, 1024, 1024,
      bq, bk, bv, nullptr, nullptr);

  // c[b,d] += diag-sums of Q[b] @ K[b]^T  (batched, M=N=K=1024, G not stored)
  gemm_mfma<3><<<dim3(4,4,16), 512, 0, stream>>>(
      Qb, 1024, 1048576L, Kb, 1024, 1048576L, nullptr, nullptr, nullptr, 0, 1024,
      nullptr, nullptr, nullptr, nullptr, cbuf);

  filter_kernel<<<16, 1024, 0, stream>>>(cbuf, gf, mv);
  topk_kernel<<<1, 1024, 0, stream>>>(mv, idxb, wsm);
  context_kernel<<<8192, 256, 0, stream>>>(Vb, idxb, wsm, CT);

  // d_out = CT @ Wd + bd + x  (fp32, M=16384, N=1024, K=1024)
  gemm_mfma<2><<<dim3(4,64,1), 512, 0, stream>>>(
      CT, 1024, 0L, WdT, 1024, 0L, outp, nullptr, nullptr, 1024, 1024,
      bd, nullptr, nullptr, x, nullptr);

  ln_kernel<<<16384, 256, 0, stream>>>(outp, gamma, beta);
}

// Round 3
// 485.157 us; speedup vs baseline: 1.0285x; 1.0285x over previous
//
#include <hip/hip_runtime.h>

// HybridAttention (fp32 I/O, bf16 MFMA internals):
// x -> cast bf16 -> QKV proj (MFMA GEMM, fused N=3072, split-store Q/K/V bf16)
// -> fused {G=Q K^T tile + diagonal-sum} (G never materialized) -> bandpass
// filter (g = irfft of band mask) -> top-6 + softmax -> context = weighted V
// row-gather (bf16) -> out GEMM (+bias+residual, fp32 into d_out) -> LayerNorm
// in-place on d_out. fp32 accumulate everywhere. ws need = 142,741,952 B.
//
// R9: FULL phase rotation. R7/R8 both measured 5800 cyc/CU/tile =
// LDS(2800) + MFMA(2480) SERIALIZED: every phase was "issue reads -> MFMA
// consuming those same reads", so the lgkm drain was exposed in-phase and the
// barrier lockstep made the whole CU alternate LDS-burst/MFMA-burst. R9
// pipelines one phase deep: each phase's MFMA consumes operands read in the
// PREVIOUS phase while issuing the NEXT phase's reads. 4 operand buffers
// rotate: Ph1 mfma(avA,bvA)|read{avB,bvB}; Ph2 mfma(avB,bvB)|read{avA'};
// Ph3 mfma(avA',bvA)|read{avB'}; Ph4 mfma(avB',bvB)|read R1(t+1). 2 barriers
// per tile: Ph3-start (B(p)+A(p,m0) free -> stage B0/B1/A0(t+2)) and the
// boundary bar (lgkmcnt(0)+vmcnt(6): A(p,m1) free, tile t+1 staged). Stage
// slots: A1(t+1)@Ph1, B0+B1(t+2)@Ph3, A0(t+2)@Ph4; vmcnt(6) = 3 half-tiles in
// flight, never drained in steady state. XOR-swizzled LDS as in R6-R8.

typedef unsigned short u16;
typedef unsigned int   u32;
typedef __attribute__((ext_vector_type(8))) __bf16 bf16x8;
typedef __attribute__((ext_vector_type(4))) float  floatx4;

#define HIDn 1024

__device__ __forceinline__ u16 f2b(float f){ u32 i = __float_as_uint(f); return (u16)((i + 0x7fffu + ((i>>16)&1u)) >> 16); }

__device__ __forceinline__ void gl_lds16(const u16* g, u16* l){
  __builtin_amdgcn_global_load_lds((__attribute__((address_space(1))) const void*)g,
                                   (__attribute__((address_space(3))) void*)l, 16, 0, 0);
}

__device__ __forceinline__ void bar(){
  asm volatile("" ::: "memory");
  __builtin_amdgcn_s_barrier();
  asm volatile("" ::: "memory");
}

// ---------------------------------------------------------------- ws guard
__global__ void fill_kernel(float* __restrict__ out, float v, int n)
{
  const int i = blockIdx.x*blockDim.x + threadIdx.x;
  if (i < n) out[i] = v;
}

// ---------------------------------------------------------------- cast x -> bf16
__global__ __launch_bounds__(256)
void cast_kernel(const float* __restrict__ x, u16* __restrict__ xb)
{
  const int i = blockIdx.x*256 + threadIdx.x;   // 2,097,152 threads x 8 floats
  const float4* xp = (const float4*)x;
  const float4 a = xp[2*i], b = xp[2*i+1];
  uint4 o;
  o.x = (u32)f2b(a.x) | ((u32)f2b(a.y)<<16);
  o.y = (u32)f2b(a.z) | ((u32)f2b(a.w)<<16);
  o.z = (u32)f2b(b.x) | ((u32)f2b(b.y)<<16);
  o.w = (u32)f2b(b.z) | ((u32)f2b(b.w)<<16);
  ((uint4*)xb)[i] = o;
}

// ---------------------------------------------------------------- transpose+cast
// WqkvT (3072 x 1024, n-major, bf16) and WdT (1024 x 1024, bf16) from fp32 W.
__global__ __launch_bounds__(1024)
void transpose_kernel(const float* __restrict__ Wq, const float* __restrict__ Wk,
                      const float* __restrict__ Wv, const float* __restrict__ Wd,
                      u16* __restrict__ WqkvT, u16* __restrict__ WdT)
{
  __shared__ float tile[32][33];
  const int mat = blockIdx.z;
  const float* W = (mat==0)?Wq:(mat==1)?Wk:(mat==2)?Wv:Wd;
  const int k = blockIdx.y*32 + threadIdx.y;
  const int n = blockIdx.x*32 + threadIdx.x;
  tile[threadIdx.y][threadIdx.x] = W[(long)k*HIDn + n];
  __syncthreads();
  const int on = blockIdx.x*32 + threadIdx.y;
  const int ok = blockIdx.y*32 + threadIdx.x;
  const u16 val = f2b(tile[threadIdx.x][threadIdx.y]);
  if (mat < 3) WqkvT[(long)(mat*HIDn + on)*HIDn + ok] = val;
  else         WdT[(long)on*HIDn + ok] = val;
}

// ---------------------------------------------------------------- gf + zero c
// g[d] = (2*sum_{f=205..511} cos(2 pi f d/1024) + (-1)^d) / 1024^2
__global__ __launch_bounds__(1024)
void gf_kernel(float* __restrict__ gf, float* __restrict__ c)
{
  const int d = threadIdx.x;
  float s = 0.f;
  for (int f = 205; f < 512; ++f){
    int p = (f*d) & 1023;
    s += cosf(6.283185307179586f * (float)p * (1.0f/1024.0f));
  }
  gf[d] = (2.f*s + ((d & 1) ? -1.f : 1.f)) * (1.0f/1048576.0f);
  #pragma unroll
  for (int b = 0; b < 16; ++b) c[b*1024 + d] = 0.f;
}

// ---------------------------------------------------------------- MFMA GEMM
// C(M x N) = A(M x K) * Bt(N x K)^T ; bf16 in, fp32 acc. 256x256 tile, 8 waves
// (2Mx4N), per-wave 128x64 (acc[8][4] 16x16x32 frags), BK=64, fully-rotated
// 4-phase pipeline (see header). Requires K % 64 == 0, K >= 128.
// EPI 0: +fp32 bias (select by bx>>2), bf16 split-store to C0/o1/o2 (Q/K/V).
// EPI 2: +fp32 bias +fp32 resid, fp32 out (hidden+residual -> d_out).
// EPI 3: no C store; diagonal-sum tile into cbuf[bz*1024 + d] (atomics).
template<int EPI>
__global__ __launch_bounds__(512, 2)
void gemm_mfma(const u16* __restrict__ A, int lda, long sA,
               const u16* __restrict__ Bt, int ldb, long sB,
               void* __restrict__ C0, u16* __restrict__ o1, u16* __restrict__ o2,
               int ldc, int K,
               const float* __restrict__ b0, const float* __restrict__ b1,
               const float* __restrict__ b2, const float* __restrict__ resid,
               float* __restrict__ cbuf)
{
  __shared__ __align__(16) u16 As[2][16384];   // 2 x (256 rows x 64 k)
  __shared__ __align__(16) u16 Bs[2][16384];
  __shared__ float bins[512];

  const int bx = blockIdx.x, by = blockIdx.y, bz = blockIdx.z;
  const int tid  = threadIdx.x;
  const int wave = tid >> 6, lane = tid & 63;
  const int waveM = wave >> 2, waveN = wave & 3;
  const int qd = lane >> 4, ln = lane & 15, rl = ln & 7;
  const u16* Ab = A  + (long)bz * sA;
  const u16* Bb = Bt + (long)bz * sB;
  const int aRow0 = by * 256, bRow0 = bx * 256;
  const int nt = K >> 6;

  // staging: slot s = wave*128 + lane within a 128-row half (8 chunks/row)
  const int s0 = wave*128 + lane;
  const int r0 = s0 >> 3, r1 = r0 + 8;
  const int kc = ((s0 & 7) ^ (r0 & 7)) * 8;          // pre-swizzled source chunk
  const long aOff0 = (long)(aRow0 + r0)*lda + kc;
  const long aOff1 = (long)(aRow0 + r1)*lda + kc;
  const long bOff0 = (long)(bRow0 + r0)*ldb + kc;
  const long bOff1 = (long)(bRow0 + r1)*ldb + kc;
  const int dstW = wave*1024;                         // u16, wave-uniform

#define STAGE_A(p, h, kt) do{ \
    gl_lds16(Ab + aOff0 + (long)(h)*128*lda + (kt), &As[p][(h)*8192 + dstW]); \
    gl_lds16(Ab + aOff1 + (long)(h)*128*lda + (kt), &As[p][(h)*8192 + dstW + 512]); }while(0)
#define STAGE_B(p, h, kt) do{ \
    gl_lds16(Bb + bOff0 + (long)(h)*128*ldb + (kt), &Bs[p][(h)*8192 + dstW]); \
    gl_lds16(Bb + bOff1 + (long)(h)*128*ldb + (kt), &Bs[p][(h)*8192 + dstW + 512]); }while(0)

  if (EPI == 3) bins[tid] = 0.f;       // synced by prologue barrier

  floatx4 acc[8][4];
  const floatx4 z4 = {0.f, 0.f, 0.f, 0.f};
  #pragma unroll
  for (int i=0;i<8;++i)
    #pragma unroll
    for (int j=0;j<4;++j) acc[i][j] = z4;

  // read addressing: row R frag at u16 offset R*64 + ((chunk)^(R&7))*8
  const int aRd = (waveM*128 + ln)*64;   // + mi*1024 (+4096 for m-half 1)
  const int bRd = (waveN*64  + ln)*64;   // + ni*1024
  const int csw0 = ((0 + qd) ^ rl) * 8;  // kk=0 chunk
  const int csw1 = ((4 + qd) ^ rl) * 8;  // kk=1 chunk

  // ---- prologue: tile0 {B0,B1,A0,A1}, tile1 {B0,B1,A0}; wait tile0 (vmcnt 6)
  STAGE_B(0,0,0); STAGE_B(0,1,0); STAGE_A(0,0,0); STAGE_A(0,1,0);
  STAGE_B(1,0,64); STAGE_B(1,1,64); STAGE_A(1,0,64);
  asm volatile("s_waitcnt vmcnt(6)" ::: "memory");
  __builtin_amdgcn_s_barrier();
  asm volatile("" ::: "memory");

  bf16x8 avA[4], avB[4], bvA[4], bvB[4];
  // R1(t=0): A(m0,kk0) + B(kk0)
  {
    const u16* Ap = &As[0][0]; const u16* Bp = &Bs[0][0];
    avA[0] = *(const bf16x8*)(Ap + aRd + 0*1024 + csw0);
    #pragma unroll
    for (int ni=0;ni<4;++ni) bvA[ni] = *(const bf16x8*)(Bp + bRd + ni*1024 + csw0);
    #pragma unroll
    for (int mi=1;mi<4;++mi) avA[mi] = *(const bf16x8*)(Ap + aRd + mi*1024 + csw0);
  }
  __builtin_amdgcn_sched_barrier(0);

  for (int t = 0; t < nt; ++t){
    const int p = t & 1;
    const u16* Ap = &As[p][0];
    const u16* Bp = &Bs[p][0];
    const int k1 = (t+1) << 6, k2 = (t+2) << 6;

    // ---- Ph1: issue R2 {avB=A(m0,kk1), bvB=B(kk1)}; stage A1(t+1);
    //           MFMA kk0 x m-half0 (avA,bvA in regs from R1)
    avB[0] = *(const bf16x8*)(Ap + aRd + 0*1024 + csw1);
    #pragma unroll
    for (int ni=0;ni<4;++ni) bvB[ni] = *(const bf16x8*)(Bp + bRd + ni*1024 + csw1);
    #pragma unroll
    for (int mi=1;mi<4;++mi) avB[mi] = *(const bf16x8*)(Ap + aRd + mi*1024 + csw1);
    if (t+1 < nt) STAGE_A(p^1, 1, k1);
    __builtin_amdgcn_sched_barrier(0);
    __builtin_amdgcn_s_setprio(1);
    #pragma unroll
    for (int mi=0;mi<4;++mi)
      #pragma unroll
      for (int ni=0;ni<4;++ni)
        acc[mi][ni] = __builtin_amdgcn_mfma_f32_16x16x32_bf16(avA[mi], bvA[ni], acc[mi][ni], 0,0,0);
    __builtin_amdgcn_s_setprio(0);
    __builtin_amdgcn_sched_barrier(0);

    // ---- Ph2: issue R3 {avA=A(m1,kk0)}; MFMA kk1 x m-half0 (avB,bvB)
    #pragma unroll
    for (int mi=0;mi<4;++mi) avA[mi] = *(const bf16x8*)(Ap + aRd + 4096 + mi*1024 + csw0);
    __builtin_amdgcn_sched_barrier(0);
    __builtin_amdgcn_s_setprio(1);
    #pragma unroll
    for (int mi=0;mi<4;++mi)
      #pragma unroll
      for (int ni=0;ni<4;++ni)
        acc[mi][ni] = __builtin_amdgcn_mfma_f32_16x16x32_bf16(avB[mi], bvB[ni], acc[mi][ni], 0,0,0);
    __builtin_amdgcn_s_setprio(0);
    __builtin_amdgcn_sched_barrier(0);
    bar();   // all waves' R1+R2 complete -> B(p) and A(p,m0) free for staging

    // ---- Ph3: issue R4 {avB=A(m1,kk1)}; stage B0+B1(t+2);
    //           MFMA kk0 x m-half1 (avA from R3, bvA reused)
    #pragma unroll
    for (int mi=0;mi<4;++mi) avB[mi] = *(const bf16x8*)(Ap + aRd + 4096 + mi*1024 + csw1);
    if (t+2 < nt){ STAGE_B(p, 0, k2); STAGE_B(p, 1, k2); }
    __builtin_amdgcn_sched_barrier(0);
    __builtin_amdgcn_s_setprio(1);
    #pragma unroll
    for (int mi=0;mi<4;++mi)
      #pragma unroll
      for (int ni=0;ni<4;++ni)
        acc[4+mi][ni] = __builtin_amdgcn_mfma_f32_16x16x32_bf16(avA[mi], bvA[ni], acc[4+mi][ni], 0,0,0);
    __builtin_amdgcn_s_setprio(0);
    __builtin_amdgcn_sched_barrier(0);

    // ---- Ph4: stage A0(t+2); counted vmcnt + lgkm drain + boundary bar;
    //           issue R1(t+1) from buffer p^1; MFMA kk1 x m-half1 (avB,bvB)
    if (t+2 < nt){
      STAGE_A(p, 0, k2);
      asm volatile("s_waitcnt vmcnt(6)" ::: "memory");   // tile t+1 fully staged
    } else if (t+1 < nt){
      asm volatile("s_waitcnt vmcnt(0)" ::: "memory");   // drain tail
    }
    if (t+1 < nt){
      asm volatile("s_waitcnt lgkmcnt(0)" ::: "memory"); // all R3/R4 reads landed
      __builtin_amdgcn_sched_barrier(0);
      bar();                             // next tile's buffer ready; A(p,m1) free
      const u16* An = &As[p^1][0];
      const u16* Bn = &Bs[p^1][0];
      avA[0] = *(const bf16x8*)(An + aRd + 0*1024 + csw0);
      #pragma unroll
      for (int ni=0;ni<4;++ni) bvA[ni] = *(const bf16x8*)(Bn + bRd + ni*1024 + csw0);
      #pragma unroll
      for (int mi=1;mi<4;++mi) avA[mi] = *(const bf16x8*)(An + aRd + mi*1024 + csw0);
      __builtin_amdgcn_sched_barrier(0);
    }
    __builtin_amdgcn_s_setprio(1);
    #pragma unroll
    for (int mi=0;mi<4;++mi)
      #pragma unroll
      for (int ni=0;ni<4;++ni)
        acc[4+mi][ni] = __builtin_amdgcn_mfma_f32_16x16x32_bf16(avB[mi], bvB[ni], acc[4+mi][ni], 0,0,0);
    __builtin_amdgcn_s_setprio(0);
  }
#undef STAGE_A
#undef STAGE_B

  if (EPI == 3){
    // G[l][m] at frag(mi,ni) reg r lane(qd,ln):
    //   l-m = (aRow0-bRow0) + 128*waveM - 64*waveN + 16*(mi-ni) + 4*qd + r - ln
    float dsum[11][4];
    #pragma unroll
    for (int dd=0; dd<11; ++dd)
      #pragma unroll
      for (int r=0;r<4;++r) dsum[dd][r] = 0.f;
    #pragma unroll
    for (int mi=0;mi<8;++mi)
      #pragma unroll
      for (int ni=0;ni<4;++ni){
        const int dd = mi - ni + 3;
        #pragma unroll
        for (int r=0;r<4;++r) dsum[dd][r] += acc[mi][ni][r];
      }
    const int base = 255 + 128*waveM - 64*waveN + 4*qd - ln;
    #pragma unroll
    for (int dd=0; dd<11; ++dd)
      #pragma unroll
      for (int r=0;r<4;++r)
        atomicAdd(&bins[base + 16*(dd-3) + r], dsum[dd][r]);
    __syncthreads();
    if (tid < 511){
      const int d = (aRow0 - bRow0 + tid - 255) & 1023;
      atomicAdd(cbuf + bz*1024 + d, bins[tid]);
    }
    return;
  }

  // epilogue: C/D layout col = lane&15, row = (lane>>4)*4 + reg
  if (EPI == 0){
    const int which = bx >> 2;                 // 256-tile never crosses 1024
    const float* bp = (which==0) ? b0 : ((which==1) ? b1 : b2);
    u16* Cb = (which==0) ? (u16*)C0 : ((which==1) ? o1 : o2);
    const int nb = bRow0 & 1023;
    #pragma unroll
    for (int mi=0;mi<8;++mi){
      const int gm = aRow0 + waveM*128 + mi*16 + qd*4;
      #pragma unroll
      for (int ni=0;ni<4;++ni){
        const int nl = nb + waveN*64 + ni*16 + ln;
        const float bias = bp[nl];
        #pragma unroll
        for (int r=0;r<4;++r) Cb[(long)(gm+r)*ldc + nl] = f2b(acc[mi][ni][r] + bias);
      }
    }
  } else {  // EPI == 2
    float* C = (float*)C0;
    #pragma unroll
    for (int mi=0;mi<8;++mi){
      const int gm = aRow0 + waveM*128 + mi*16 + qd*4;
      #pragma unroll
      for (int ni=0;ni<4;++ni){
        const int gn = bRow0 + waveN*64 + ni*16 + ln;
        const float bias = b0[gn];
        #pragma unroll
        for (int r=0;r<4;++r)
          C[(long)(gm+r)*ldc + gn] = acc[mi][ni][r] + bias + resid[(long)(gm+r)*ldc + gn];
      }
    }
  }
}

// ---------------------------------------------------------------- filter
// mv[b,n] = sum_m c[b,m] * gf[(n-m)&1023]
__global__ __launch_bounds__(1024)
void filter_kernel(const float* __restrict__ c, const float* __restrict__ gf,
                   float* __restrict__ mv)
{
  __shared__ float carr[1024];
  __shared__ float gsh[1024];
  const int b = blockIdx.x, l = threadIdx.x;
  carr[l] = c[b*1024 + l]; gsh[l] = gf[l];
  __syncthreads();
  float o = 0.f;
  #pragma unroll 4
  for (int m = 0; m < 1024; ++m) o += carr[m] * gsh[(l - m) & 1023];
  mv[b*1024 + l] = o;
}

// ---------------------------------------------------------------- top-6 + softmax
__global__ __launch_bounds__(1024)
void topk_kernel(const float* __restrict__ mv, int* __restrict__ idxout,
                 float* __restrict__ wout)
{
  __shared__ float vals[1024];
  __shared__ float rv[1024];
  __shared__ int   ri[1024];
  __shared__ int   chosen[6];
  const int t = threadIdx.x;
  float s = 0.f;
  #pragma unroll
  for (int b = 0; b < 16; ++b) s += mv[b*1024 + t];
  vals[t] = s;
  __syncthreads();
  for (int r = 0; r < 6; ++r){
    rv[t] = vals[t]; ri[t] = t; __syncthreads();
    for (int off = 512; off > 0; off >>= 1){
      if (t < off){
        const float v2 = rv[t+off]; const int i2 = ri[t+off];
        if (v2 > rv[t] || (v2 == rv[t] && i2 < ri[t])){ rv[t] = v2; ri[t] = i2; }
      }
      __syncthreads();
    }
    if (t == 0){ chosen[r] = ri[0]; idxout[r] = ri[0]; }
    __syncthreads();
    if (t == chosen[r]) vals[t] = -3.0e38f;
    __syncthreads();
  }
  if (t < 16){
    float w[6]; float mx = -3.0e38f;
    #pragma unroll
    for (int i = 0; i < 6; ++i){ w[i] = mv[t*1024 + chosen[i]]; mx = fmaxf(mx, w[i]); }
    float sum = 0.f;
    #pragma unroll
    for (int i = 0; i < 6; ++i){ w[i] = expf(w[i] - mx); sum += w[i]; }
    #pragma unroll
    for (int i = 0; i < 6; ++i) wout[t*6 + i] = w[i] / sum;
  }
}

// ---------------------------------------------------------------- context gather
// CT[b*1024+l, :] = sum_i w[b,i] * V[b, (l+idx_i)&1023, :]   (bf16 in/out)
__global__ __launch_bounds__(256)
void context_kernel(const u16* __restrict__ Vb, const int* __restrict__ idx,
                    const float* __restrict__ w, u16* __restrict__ CT)
{
  const int row = blockIdx.x*2 + (threadIdx.x >> 7);
  const int b = row >> 10, l = row & 1023;
  const int t = threadIdx.x & 127;       // chunk of 8 channels
  float wl[6]; int id[6];
  #pragma unroll
  for (int i = 0; i < 6; ++i){ id[i] = idx[i]; wl[i] = w[b*6 + i]; }
  float acc[8] = {0,0,0,0,0,0,0,0};
  #pragma unroll
  for (int i = 0; i < 6; ++i){
    const long src = (long)b*1024 + ((l + id[i]) & 1023);
    const uint4 pk = *(const uint4*)(Vb + src*1024 + t*8);
    const float ww = wl[i];
    union{float f; u32 u;} cv;
    cv.u = pk.x<<16;          acc[0] += ww*cv.f;
    cv.u = pk.x & 0xffff0000u; acc[1] += ww*cv.f;
    cv.u = pk.y<<16;          acc[2] += ww*cv.f;
    cv.u = pk.y & 0xffff0000u; acc[3] += ww*cv.f;
    cv.u = pk.z<<16;          acc[4] += ww*cv.f;
    cv.u = pk.z & 0xffff0000u; acc[5] += ww*cv.f;
    cv.u = pk.w<<16;          acc[6] += ww*cv.f;
    cv.u = pk.w & 0xffff0000u; acc[7] += ww*cv.f;
  }
  uint4 o;
  o.x = (u32)f2b(acc[0]) | ((u32)f2b(acc[1])<<16);
  o.y = (u32)f2b(acc[2]) | ((u32)f2b(acc[3])<<16);
  o.z = (u32)f2b(acc[4]) | ((u32)f2b(acc[5])<<16);
  o.w = (u32)f2b(acc[6]) | ((u32)f2b(acc[7])<<16);
  *(uint4*)(CT + (long)row*1024 + t*8) = o;
}

// ---------------------------------------------------------------- layernorm (in-place fp32)
__global__ __launch_bounds__(256)
void ln_kernel(float* __restrict__ io, const float* __restrict__ gamma,
               const float* __restrict__ beta)
{
  __shared__ float s1[256];
  __shared__ float s2[256];
  const int row = blockIdx.x, t = threadIdx.x;
  float4 v = ((const float4*)(io + (long)row*1024))[t];
  s1[t] = v.x+v.y+v.z+v.w;
  s2[t] = v.x*v.x+v.y*v.y+v.z*v.z+v.w*v.w;
  __syncthreads();
  for (int off = 128; off > 0; off >>= 1){
    if (t < off){ s1[t] += s1[t+off]; s2[t] += s2[t+off]; }
    __syncthreads();
  }
  const float mu  = s1[0] * (1.f/1024.f);
  const float var = fmaxf(s2[0] * (1.f/1024.f) - mu*mu, 0.f);
  const float rstd = rsqrtf(var + 1e-12f);
  const float4 g  = ((const float4*)gamma)[t];
  const float4 be = ((const float4*)beta)[t];
  float4 o;
  o.x = (v.x-mu)*rstd*g.x + be.x;
  o.y = (v.y-mu)*rstd*g.y + be.y;
  o.z = (v.z-mu)*rstd*g.z + be.z;
  o.w = (v.w-mu)*rstd*g.w + be.w;
  ((float4*)(io + (long)row*1024))[t] = o;
}

// ---------------------------------------------------------------- launch
extern "C" void kernel_launch(void* const* d_in, const int* in_sizes, int n_in,
                              void* d_out, int out_size, void* d_ws, size_t ws_size,
                              hipStream_t stream)
{
  (void)in_sizes; (void)n_in;
  const float* x     = (const float*)d_in[0];
  // d_in[1] attention_mask: zeros, unused by the reference math
  const float* Wq    = (const float*)d_in[2];
  const float* bq    = (const float*)d_in[3];
  const float* Wk    = (const float*)d_in[4];
  const float* bk    = (const float*)d_in[5];
  const float* Wv    = (const float*)d_in[6];
  const float* bv    = (const float*)d_in[7];
  const float* Wd    = (const float*)d_in[8];
  const float* bd    = (const float*)d_in[9];
  const float* gamma = (const float*)d_in[10];
  const float* beta  = (const float*)d_in[11];
  float* outp = (float*)d_out;

  // ws layout (bytes), total 142,741,952:
  // xb 32M | Qb 32M | Kb 32M | Vb 32M | WqkvT 6M | WdT 2M | cbuf 64K | mv 64K | gf 4K | idx | w
  const size_t NEED = 142741952UL;
  if (ws_size < NEED){
    // guard: encode ws_size into the output so a failing absmax reveals it
    const int n = out_size/2;
    fill_kernel<<<(n+255)/256, 256, 0, stream>>>(outp, (float)ws_size, n);
    return;
  }
  char* ws = (char*)d_ws;
  u16*  xb    = (u16*)(ws);
  u16*  Qb    = (u16*)(ws + 33554432L);
  u16*  Kb    = (u16*)(ws + 67108864L);
  u16*  Vb    = (u16*)(ws + 100663296L);
  u16*  WqkvT = (u16*)(ws + 134217728L);
  u16*  WdT   = (u16*)(ws + 140509184L);
  float* cbuf = (float*)(ws + 142606336L);
  float* mv   = (float*)(ws + 142671872L);
  float* gf   = (float*)(ws + 142737408L);
  int*   idxb = (int*)  (ws + 142741504L);
  float* wsm  = (float*)(ws + 142741568L);
  u16*  CT    = Qb;   // reuse: Q's last reader is the G-gemm

  cast_kernel<<<8192, 256, 0, stream>>>(x, xb);
  transpose_kernel<<<dim3(32,32,4), dim3(32,32), 0, stream>>>(Wq, Wk, Wv, Wd, WqkvT, WdT);
  gf_kernel<<<1, 1024, 0, stream>>>(gf, cbuf);

  // Q|K|V = x @ [Wq|Wk|Wv] + bias (M=16384, N=3072, K=1024), bf16 split-store
  gemm_mfma<0><<<dim3(12,64,1), 512, 0, stream>>>(
      xb, 1024, 0L, WqkvT, 1024, 0L, Qb, Kb, Vb, 1024, 1024,
      bq, bk, bv, nullptr, nullptr);

  // c[b,d] += diag-sums of Q[b] @ K[b]^T  (batched, M=N=K=1024, G not stored)
  gemm_mfma<3><<<dim3(4,4,16), 512, 0, stream>>>(
      Qb, 1024, 1048576L, Kb, 1024, 1048576L, nullptr, nullptr, nullptr, 0, 1024,
      nullptr, nullptr, nullptr, nullptr, cbuf);

  filter_kernel<<<16, 1024, 0, stream>>>(cbuf, gf, mv);
  topk_kernel<<<1, 1024, 0, stream>>>(mv, idxb, wsm);
  context_kernel<<<8192, 256, 0, stream>>>(Vb, idxb, wsm, CT);

  // d_out = CT @ Wd + bd + x  (fp32, M=16384, N=1024, K=1024)
  gemm_mfma<2><<<dim3(4,64,1), 512, 0, stream>>>(
      CT, 1024, 0L, WdT, 1024, 0L, outp, nullptr, nullptr, 1024, 1024,
      bd, nullptr, nullptr, x, nullptr);

  ln_kernel<<<16384, 256, 0, stream>>>(outp, gamma, beta);
}